// Round 1
// baseline (71.252 us; speedup 1.0000x reference)
//
#include <hip/hip_runtime.h>
#include <math.h>

// Input:  x (16, 31, 256, 256) float32
// Output: sqrt(v^2 + h^2 + 1e-6), v = x[y+1]-x[y-1], h = x[:,x+1]-x[:,x-1],
// zero padding at the borders.

#define IMG_H 256
#define IMG_W 256
#define EPS   1e-6f

__global__ __launch_bounds__(256) void grad_mag_kernel(
    const float* __restrict__ in, float* __restrict__ out)
{
    const int tid    = threadIdx.x;
    const int lane   = tid & 63;        // float4 slot within row (64 * 4 = 256 px)
    const int rowsub = tid >> 6;        // 0..3 : row within this block

    // 64 row-blocks per plane (4 rows each), planes = 16*31 = 496
    const int blocks_per_plane = IMG_H / 4 / 1 / 16;   // placeholder guard (see below)
    (void)blocks_per_plane;

    const int y_block = blockIdx.x & 63;        // 64 blocks of 4 rows = 256 rows
    const long long plane = blockIdx.x >> 6;    // 0..495

    const int y  = y_block * 4 + rowsub;
    const int x0 = lane * 4;

    const float* __restrict__ p = in + plane * (long long)(IMG_H * IMG_W);
    float*       __restrict__ q = out + plane * (long long)(IMG_H * IMG_W);

    const float4 zero4 = make_float4(0.f, 0.f, 0.f, 0.f);

    const float4 cur = *reinterpret_cast<const float4*>(p + y * IMG_W + x0);
    const float4 up  = (y > 0)         ? *reinterpret_cast<const float4*>(p + (y - 1) * IMG_W + x0) : zero4;
    const float4 dn  = (y < IMG_H - 1) ? *reinterpret_cast<const float4*>(p + (y + 1) * IMG_W + x0) : zero4;

    // Horizontal neighbors via wave shuffle: each wave spans exactly one row.
    float left  = __shfl_up(cur.w, 1);   // lane-1's last element
    float right = __shfl_down(cur.x, 1); // lane+1's first element
    if (lane == 0)  left  = 0.f;         // zero padding at x = -1
    if (lane == 63) right = 0.f;         // zero padding at x = 256

    float4 h, v, o;
    h.x = cur.y - left;
    h.y = cur.z - cur.x;
    h.z = cur.w - cur.y;
    h.w = right - cur.z;

    v.x = dn.x - up.x;
    v.y = dn.y - up.y;
    v.z = dn.z - up.z;
    v.w = dn.w - up.w;

    o.x = sqrtf(v.x * v.x + h.x * h.x + EPS);
    o.y = sqrtf(v.y * v.y + h.y * h.y + EPS);
    o.z = sqrtf(v.z * v.z + h.z * h.z + EPS);
    o.w = sqrtf(v.w * v.w + h.w * h.w + EPS);

    *reinterpret_cast<float4*>(q + y * IMG_W + x0) = o;
}

extern "C" void kernel_launch(void* const* d_in, const int* in_sizes, int n_in,
                              void* d_out, int out_size, void* d_ws, size_t ws_size,
                              hipStream_t stream)
{
    const float* x = (const float*)d_in[0];
    float* out = (float*)d_out;

    // planes = total elements / (256*256)
    const int planes = in_sizes[0] / (IMG_H * IMG_W);   // 16*31 = 496
    const int grid = planes * (IMG_H / 4);              // 4 rows per 256-thread block

    grad_mag_kernel<<<grid, 256, 0, stream>>>(x, out);
}

// Round 2
// 44.962 us; speedup vs baseline: 1.5847x; 1.5847x over previous
//
#include <hip/hip_runtime.h>
#include <math.h>

// Input:  x (16, 31, 256, 256) float32
// Output: sqrt(v^2 + h^2 + 1e-6), v = x[y+1]-x[y-1], h = x[:,x+1]-x[:,x-1],
// zero padding at the borders.
//
// R2: 8-row register strip per lane. Each wave (64 lanes x float4) spans one
// full 256-px row; each lane loads rows y0-1..y0+8 into registers up front
// (10 outstanding 16B loads -> deep MLP), then computes 8 outputs reusing
// rows in-register (vertical read amplification 3x -> 1.25x). Non-temporal
// stores keep the streaming output out of L2/L3.

#define IMG_H 256
#define IMG_W 256
#define EPS   1e-6f
#define STRIP 8                    // output rows per wave/lane
#define WAVES_PER_BLOCK 4
#define ROWS_PER_BLOCK (STRIP * WAVES_PER_BLOCK)   // 32

typedef float f32x4 __attribute__((ext_vector_type(4)));

__global__ __launch_bounds__(256) void grad_mag_kernel(
    const float* __restrict__ in, float* __restrict__ out)
{
    const int tid  = threadIdx.x;
    const int lane = tid & 63;
    const int wv   = tid >> 6;                    // wave within block: 0..3

    const int band        = blockIdx.x & 7;       // 8 bands of 32 rows / plane
    const long long plane = blockIdx.x >> 3;      // 0..495

    const int y0 = band * ROWS_PER_BLOCK + wv * STRIP;  // first output row
    const int x0 = lane * 4;

    const float* __restrict__ p = in  + plane * (long long)(IMG_H * IMG_W) + x0;
    float*       __restrict__ q = out + plane * (long long)(IMG_H * IMG_W) + x0;

    // Load rows y0-1 .. y0+STRIP unconditionally from a clamped address, then
    // zero out-of-range rows with a select — keeps the 10 loads branch-free
    // and back-to-back in the instruction stream.
    f32x4 r[STRIP + 2];
    #pragma unroll
    for (int i = 0; i < STRIP + 2; ++i) {
        const int y  = y0 - 1 + i;
        const int yc = y < 0 ? 0 : (y > IMG_H - 1 ? IMG_H - 1 : y);
        r[i] = *reinterpret_cast<const f32x4*>(p + (long long)yc * IMG_W);
    }
    #pragma unroll
    for (int i = 0; i < STRIP + 2; ++i) {
        const int y = y0 - 1 + i;
        if (y < 0 || y > IMG_H - 1) r[i] = (f32x4)0.f;
    }

    #pragma unroll
    for (int i = 0; i < STRIP; ++i) {
        const f32x4 up  = r[i];
        const f32x4 cur = r[i + 1];
        const f32x4 dn  = r[i + 2];

        // Horizontal neighbors across lanes (wave spans exactly one row).
        float left  = __shfl_up(cur.w, 1);
        float right = __shfl_down(cur.x, 1);
        if (lane == 0)  left  = 0.f;     // zero pad at x = -1
        if (lane == 63) right = 0.f;     // zero pad at x = 256

        f32x4 h, v, o;
        h.x = cur.y - left;
        h.y = cur.z - cur.x;
        h.z = cur.w - cur.y;
        h.w = right - cur.z;
        v = dn - up;

        o.x = sqrtf(v.x * v.x + h.x * h.x + EPS);
        o.y = sqrtf(v.y * v.y + h.y * h.y + EPS);
        o.z = sqrtf(v.z * v.z + h.z * h.z + EPS);
        o.w = sqrtf(v.w * v.w + h.w * h.w + EPS);

        __builtin_nontemporal_store(
            o, reinterpret_cast<f32x4*>(q + (long long)(y0 + i) * IMG_W));
    }
}

extern "C" void kernel_launch(void* const* d_in, const int* in_sizes, int n_in,
                              void* d_out, int out_size, void* d_ws, size_t ws_size,
                              hipStream_t stream)
{
    const float* x = (const float*)d_in[0];
    float* out = (float*)d_out;

    const int planes = in_sizes[0] / (IMG_H * IMG_W);        // 16*31 = 496
    const int grid   = planes * (IMG_H / ROWS_PER_BLOCK);    // 496 * 8 = 3968

    grad_mag_kernel<<<grid, 256, 0, stream>>>(x, out);
}

// Round 3
// 43.241 us; speedup vs baseline: 1.6478x; 1.0398x over previous
//
#include <hip/hip_runtime.h>
#include <math.h>

// Input:  x (16, 31, 256, 256) float32
// Output: sqrt(v^2 + h^2 + 1e-6), v = x[y+1]-x[y-1], h = x[:,x+1]-x[:,x-1],
// zero padding at the borders.
//
// R3: STRIP=16 register strip per lane (read amplification 1.125x), 128-thread
// blocks (grid stays 3968 for load balance), XCD-chunked block swizzle so
// adjacent bands of a plane share an XCD L2 (halo reuse), raw v_sqrt_f32.

#define IMG_H 256
#define IMG_W 256
#define EPS   1e-6f
#define STRIP 16                   // output rows per wave/lane
#define WAVES_PER_BLOCK 2
#define ROWS_PER_BLOCK (STRIP * WAVES_PER_BLOCK)   // 32
#define BANDS (IMG_H / ROWS_PER_BLOCK)             // 8

typedef float f32x4 __attribute__((ext_vector_type(4)));

__global__ __launch_bounds__(128) void grad_mag_kernel(
    const float* __restrict__ in, float* __restrict__ out)
{
    const int tid  = threadIdx.x;
    const int lane = tid & 63;
    const int wv   = tid >> 6;                    // wave within block: 0..1

    // XCD-chunked swizzle: hardware round-robins blockIdx across 8 XCDs
    // (bid & 7 == XCD). Give XCD k the contiguous sid range
    // [k*(nwg/8), (k+1)*(nwg/8)) so adjacent bands / planes stay on one L2.
    // gridDim.x = 3968 is divisible by 8 -> bijective.
    const int chunk = gridDim.x >> 3;
    const int sid   = (blockIdx.x & 7) * chunk + (blockIdx.x >> 3);

    const int band        = sid & (BANDS - 1);
    const long long plane = sid >> 3;             // 0..495

    const int y0 = band * ROWS_PER_BLOCK + wv * STRIP;  // first output row
    const int x0 = lane * 4;

    const float* __restrict__ p = in  + plane * (long long)(IMG_H * IMG_W) + x0;
    float*       __restrict__ q = out + plane * (long long)(IMG_H * IMG_W) + x0;

    // Load rows y0-1 .. y0+STRIP unconditionally from clamped addresses
    // (branch-free, back-to-back issue -> deep MLP), then zero OOB rows.
    f32x4 r[STRIP + 2];
    #pragma unroll
    for (int i = 0; i < STRIP + 2; ++i) {
        const int y  = y0 - 1 + i;
        const int yc = y < 0 ? 0 : (y > IMG_H - 1 ? IMG_H - 1 : y);
        r[i] = *reinterpret_cast<const f32x4*>(p + (long long)yc * IMG_W);
    }
    #pragma unroll
    for (int i = 0; i < STRIP + 2; ++i) {
        const int y = y0 - 1 + i;
        if (y < 0 || y > IMG_H - 1) r[i] = (f32x4)0.f;
    }

    #pragma unroll
    for (int i = 0; i < STRIP; ++i) {
        const f32x4 up  = r[i];
        const f32x4 cur = r[i + 1];
        const f32x4 dn  = r[i + 2];

        // Horizontal neighbors across lanes (wave spans exactly one row).
        float left  = __shfl_up(cur.w, 1);
        float right = __shfl_down(cur.x, 1);
        if (lane == 0)  left  = 0.f;     // zero pad at x = -1
        if (lane == 63) right = 0.f;     // zero pad at x = 256

        f32x4 h, v, o;
        h.x = cur.y - left;
        h.y = cur.z - cur.x;
        h.z = cur.w - cur.y;
        h.w = right - cur.z;
        v = dn - up;

        o.x = __builtin_amdgcn_sqrtf(v.x * v.x + h.x * h.x + EPS);
        o.y = __builtin_amdgcn_sqrtf(v.y * v.y + h.y * h.y + EPS);
        o.z = __builtin_amdgcn_sqrtf(v.z * v.z + h.z * h.z + EPS);
        o.w = __builtin_amdgcn_sqrtf(v.w * v.w + h.w * h.w + EPS);

        __builtin_nontemporal_store(
            o, reinterpret_cast<f32x4*>(q + (long long)(y0 + i) * IMG_W));
    }
}

extern "C" void kernel_launch(void* const* d_in, const int* in_sizes, int n_in,
                              void* d_out, int out_size, void* d_ws, size_t ws_size,
                              hipStream_t stream)
{
    const float* x = (const float*)d_in[0];
    float* out = (float*)d_out;

    const int planes = in_sizes[0] / (IMG_H * IMG_W);        // 16*31 = 496
    const int grid   = planes * BANDS;                       // 496 * 8 = 3968

    grad_mag_kernel<<<grid, 128, 0, stream>>>(x, out);
}